// Round 10
// baseline (849.996 us; speedup 1.0000x reference)
//
#include <hip/hip_runtime.h>

// Problem constants
#define T_STEPS 100
#define BATCH   512
#define D0      700
#define D1      512
#define D2      20
#define M_ROWS  (T_STEPS * BATCH)   // 51200

// Output layout (floats): [s2 (T*B*20) | s1 (T*B*512) | s2 copy (T*B*20)]
#define OFF_S2A 0
#define OFF_S1  (T_STEPS * BATCH * D2)                    // 1,024,000
#define OFF_S2B (OFF_S1 + T_STEPS * BATCH * D1)           // 27,238,400

__device__ __constant__ const float kALPHA = 0.8f;
__device__ __constant__ const float kBETA  = 0.9f;
__device__ __constant__ const float kTHR   = 1.0f;

// ---------------------------------------------------------------------------
// GEMM1: C[M,512] = A[M,700] * W1[512,700]^T   (both row-major, K contiguous)
// R9 + T3-minimum 2-phase pipeline (m97 structure):
//   - DOUBLE-BUFFERED gll staging: STAGE(kt+1 -> buf^1) issued BEFORE
//     ctile(buf); ONE __syncthreads() per tile (drains vmcnt after the
//     ~2048-cy FMA phase -> loads land under compute). 23 barriers vs 44.
//   - global_load_lds staging: 8 instrs/wave/tile, ZERO staging VGPRs
//     (this is why dbuf is safe here where R3's reg-staged dbuf hit the
//     VGPR cliff). LDS 64 KB -> 2 blocks/CU, VGPR ~112 -> 4 waves/SIMD.
//   - LDS tiles row-major [row][8 chunks x 4 floats]; gll writes linear
//     (lane l of instr s -> row s*8+(l>>3), chunk l&7).
//   - Source-side XOR swizzle (m173): dest chunk cl holds source k-chunk
//     cl ^ (s&7), s = row>>3; lane's 16B source stays contiguous.
//   - Reads: ds_read_b128 covering 4 k. A-frag: 4 distinct bank-quads
//     (free). B-frag: 8 quads x 2 addrs (2-way = free, m136).
//   - fmaf chain ascending-k per output element, same order as R1-R9 ->
//     bitwise-identical spikes (absmax 0.0 across all prior rounds).
//   - K edge: 700 = 21*32 + 28; last tile clamps source to byte 2784; the
//     position holding source-chunk 7 (= 7^key) is never read by ctile<7>.
// Grid swizzle kept (FETCH 287->102 MB): XCD x = id%8 owns row-panels
// [50x,50x+50), col fastest.
// ---------------------------------------------------------------------------
constexpr int BM = 128, BN = 128, BK = 32;
constexpr int TILE_F = BM * BK;          // 4096 floats = 16 KB

template <int NCH>
__device__ __forceinline__ void ctile(const float* __restrict__ As,
                                      const float* __restrict__ Ws,
                                      int tx, int ty, float acc[8][8]) {
    const int ka = ty & 7, kb = tx & 7;
#pragma unroll
    for (int kc = 0; kc < NCH; ++kc) {          // 4 k's per chunk
        float4 av[8];
#pragma unroll
        for (int i = 0; i < 8; ++i)
            av[i] = *(const float4*)&As[(ty * 8 + i) * 32 + ((kc ^ ka) << 2)];
#pragma unroll
        for (int j = 0; j < 8; ++j) {
            const float4 b = *(const float4*)&Ws[(tx * 8 + j) * 32 + ((kc ^ kb) << 2)];
#pragma unroll
            for (int i = 0; i < 8; ++i) {       // ascending k: x,y,z,w
                acc[i][j] = fmaf(av[i].x, b.x, acc[i][j]);
                acc[i][j] = fmaf(av[i].y, b.y, acc[i][j]);
                acc[i][j] = fmaf(av[i].z, b.z, acc[i][j]);
                acc[i][j] = fmaf(av[i].w, b.w, acc[i][j]);
            }
        }
    }
}

__global__ __launch_bounds__(256)
void gemm1_kernel(const float* __restrict__ A, const float* __restrict__ W,
                  float* __restrict__ C) {
    __shared__ float As[2][TILE_F];   // 2 x 16 KB, [row][8x4], source-swizzled
    __shared__ float Ws[2][TILE_F];   // 2 x 16 KB

    // XCD-chunked remap: 1600 blocks, 8 XCDs, 200 each; col fastest.
    const int d     = blockIdx.x;
    const int xcd   = d & 7;
    const int local = d >> 3;            // 0..199
    const int brow  = xcd * 50 + (local >> 2);
    const int bcol  = local & 3;

    const int tid  = threadIdx.x;
    const int row0 = brow * BM;
    const int col0 = bcol * BN;
    const int wave = tid >> 6;
    const int lane = tid & 63;
    const int tx   = tid & 15;
    const int ty   = tid >> 4;

    float acc[8][8];
#pragma unroll
    for (int i = 0; i < 8; ++i)
#pragma unroll
        for (int j = 0; j < 8; ++j) acc[i][j] = 0.f;

    // ---- gll staging of tile kt into buffer b: wave w covers s = 4w..4w+3 ----
    auto STAGE = [&](int kt, int b) {
        const int kb0 = kt * 128;                    // byte offset of k0
        float* as = &As[b][0];
        float* ws = &Ws[b][0];
#pragma unroll
        for (int q = 0; q < 4; ++q) {
            const int s = wave * 4 + q;              // row-group 0..15
            const int r = s * 8 + (lane >> 3);       // tile row of this lane
            int koff = kb0 + (((lane & 7) ^ (s & 7)) << 4);
            if (koff > 2784) koff = 2784;            // last-tile clamp (in-row)
            const char* ga = (const char*)A + (size_t)(row0 + r) * 2800 + koff;
            const char* gw = (const char*)W + (size_t)(col0 + r) * 2800 + koff;
            __builtin_amdgcn_global_load_lds(
                (const __attribute__((address_space(1))) void*)ga,
                (__attribute__((address_space(3))) void*)(as + s * 256), 16, 0, 0);
            __builtin_amdgcn_global_load_lds(
                (const __attribute__((address_space(1))) void*)gw,
                (__attribute__((address_space(3))) void*)(ws + s * 256), 16, 0, 0);
        }
    };

    STAGE(0, 0);
    __syncthreads();                     // drain -> tile 0 ready

    int buf = 0;
    for (int kt = 0; kt < 22; ++kt) {
        if (kt < 21) STAGE(kt + 1, buf ^ 1);   // issue loads BEFORE compute
        if (kt < 21) ctile<8>(&As[buf][0], &Ws[buf][0], tx, ty, acc);
        else         ctile<7>(&As[buf][0], &Ws[buf][0], tx, ty, acc);  // 28 k
        __syncthreads();                 // one barrier/tile: drains vmcnt,
        buf ^= 1;                        // and ends all reads of `buf`
    }

#pragma unroll
    for (int i = 0; i < 8; ++i) {
        float* cp = C + (size_t)(row0 + ty * 8 + i) * D1 + col0 + tx * 8;
        float4 v0 = make_float4(acc[i][0], acc[i][1], acc[i][2], acc[i][3]);
        float4 v1 = make_float4(acc[i][4], acc[i][5], acc[i][6], acc[i][7]);
        *(float4*)(cp + 0) = v0;
        *(float4*)(cp + 4) = v1;
    }
}

// ---------------------------------------------------------------------------
// Scan 1: in-place over pre1 buffer [T, B*512]; each thread owns one neuron.
// ---------------------------------------------------------------------------
__global__ __launch_bounds__(256)
void scan1_kernel(float* __restrict__ buf) {
#pragma clang fp contract(off)
    const int idx = blockIdx.x * blockDim.x + threadIdx.x;  // 0 .. 262143
    const int stride = BATCH * D1;
    float syn = 0.f, mem = 0.f;
    float* p = buf + idx;
    for (int t = 0; t < T_STEPS; ++t) {
        const float pre = p[(size_t)t * stride];
        float a = kALPHA * syn;
        syn = a + pre;
        const float reset = (mem > kTHR) ? 1.f : 0.f;
        float bm = kBETA * mem;
        mem = (bm + syn) * (1.f - reset);
        p[(size_t)t * stride] = (mem > kTHR) ? 1.f : 0.f;
    }
}

// ---------------------------------------------------------------------------
// GEMM2: C[M,20] = S1[M,512] * W2[20,512]^T.  W2 staged in LDS (40 KB).
// 256 threads = 64 rows x 4 k-quarters; shuffle-reduce across the 4.
// ---------------------------------------------------------------------------
__global__ __launch_bounds__(256)
void gemm2_kernel(const float* __restrict__ S1, const float* __restrict__ W2,
                  float* __restrict__ C) {
    __shared__ float Wsh[D2 * D1];  // 10240 floats = 40 KB
    for (int i = threadIdx.x; i < (D2 * D1) / 4; i += 256)
        ((float4*)Wsh)[i] = ((const float4*)W2)[i];
    __syncthreads();

    const int r  = threadIdx.x >> 2;   // 0..63
    const int kq = threadIdx.x & 3;    // k quarter (128 each)
    const int m  = blockIdx.x * 64 + r;

    const float4* src = (const float4*)(S1 + (size_t)m * D1 + kq * 128);
    float acc[D2];
#pragma unroll
    for (int o = 0; o < D2; ++o) acc[o] = 0.f;

    for (int j = 0; j < 32; ++j) {
        const float4 v = src[j];
        const float* wbase = Wsh + kq * 128 + j * 4;
#pragma unroll
        for (int o = 0; o < D2; ++o) {
            const float4 w = *(const float4*)(wbase + o * D1);
            acc[o] += v.x * w.x + v.y * w.y + v.z * w.z + v.w * w.w;
        }
    }
    // reduce over the 4 k-quarters (consecutive lanes)
#pragma unroll
    for (int o = 0; o < D2; ++o) {
        acc[o] += __shfl_xor(acc[o], 1);
        acc[o] += __shfl_xor(acc[o], 2);
    }
    if (kq == 0) {
        float* cp = C + (size_t)m * D2;
#pragma unroll
        for (int o = 0; o < D2; o += 4)
            *(float4*)(cp + o) = make_float4(acc[o], acc[o + 1], acc[o + 2], acc[o + 3]);
    }
}

// ---------------------------------------------------------------------------
// Scan 2: in-place over pre2 [T, B*20]; also writes the duplicate s2 slot.
// ---------------------------------------------------------------------------
__global__ __launch_bounds__(256)
void scan2_kernel(float* __restrict__ buf, float* __restrict__ dup) {
#pragma clang fp contract(off)
    const int idx = blockIdx.x * blockDim.x + threadIdx.x;  // 0 .. 10239
    const int stride = BATCH * D2;
    float syn = 0.f, mem = 0.f;
    for (int t = 0; t < T_STEPS; ++t) {
        const size_t off = (size_t)t * stride + idx;
        const float pre = buf[off];
        float a = kALPHA * syn;
        syn = a + pre;
        const float reset = (mem > kTHR) ? 1.f : 0.f;
        float bm = kBETA * mem;
        mem = (bm + syn) * (1.f - reset);
        const float s = (mem > kTHR) ? 1.f : 0.f;
        buf[off] = s;
        dup[off] = s;
    }
}

// ---------------------------------------------------------------------------
extern "C" void kernel_launch(void* const* d_in, const int* in_sizes, int n_in,
                              void* d_out, int out_size, void* d_ws, size_t ws_size,
                              hipStream_t stream) {
    const float* x  = (const float*)d_in[0];   // [100, 512, 700]
    const float* W1 = (const float*)d_in[1];   // [512, 700]
    const float* W2 = (const float*)d_in[2];   // [20, 512]
    float* out = (float*)d_out;

    float* s2a = out + OFF_S2A;   // [T,B,20]  (pre2 then s2)
    float* s1  = out + OFF_S1;    // [T,B,512] (pre1 then s1)
    float* s2b = out + OFF_S2B;   // [T,B,20]  duplicate s2

    // 1) pre1 = x @ W1^T  -> s1 slot  (gll dbuf 2-phase pipeline)
    gemm1_kernel<<<(M_ROWS / BM) * (D1 / BN), 256, 0, stream>>>(x, W1, s1);

    // 2) scan layer 1 in place (pre1 -> spikes)
    scan1_kernel<<<(BATCH * D1) / 256, 256, 0, stream>>>(s1);

    // 3) pre2 = s1 @ W2^T -> s2a slot
    gemm2_kernel<<<M_ROWS / 64, 256, 0, stream>>>(s1, W2, s2a);

    // 4) scan layer 2 in place + duplicate
    scan2_kernel<<<(BATCH * D2) / 256, 256, 0, stream>>>(s2a, s2b);
}